// Round 1
// baseline (845.952 us; speedup 1.0000x reference)
//
#include <hip/hip_runtime.h>
#include <hip/hip_bf16.h>
#include <stdint.h>

typedef __attribute__((ext_vector_type(8))) short short8;
typedef __attribute__((ext_vector_type(4))) float floatx4;

#define B_TOT 1024
#define N_TOK 128
#define C_DIM 128
#define NHEAD 8
#define NW_MASK 64

// ---- workspace layout (bytes) ----
#define BIAS_OFF 0         // [8][128][128] fp32                     524288
#define WQ_OFF   524288    // [8h][3p][16oc][128kk] ushort            98304
#define WK_OFF   622592    // [8h][3p][16oc][128kk] ushort            98304
#define WV_OFF   720896    // [8h][16oc][128kk] ushort                32768
#define WPT_OFF  753664    // [4hp][128n][32kk] ushort                32768
#define WS_BYTES 786432

#define MFMA(a, b, c) __builtin_amdgcn_mfma_f32_16x16x32_bf16((a), (b), (c), 0, 0, 0)

__device__ __forceinline__ float bf2f(ushort u) {
  union { uint32_t u; float f; } v; v.u = ((uint32_t)u) << 16; return v.f;
}
__device__ __forceinline__ ushort f2bf(float f) {
  uint32_t u = __float_as_uint(f);
  return (ushort)((u + 0x7FFFu + ((u >> 16) & 1u)) >> 16);  // RNE
}
// full-RNE 3-way split (used once, in prep)
__device__ __forceinline__ void split3(float f, ushort& h, ushort& m, ushort& l) {
  h = f2bf(f);  float r  = f - bf2f(h);
  m = f2bf(r);  float r2 = r - bf2f(m);
  l = f2bf(r2);
}
// cheap split: h,m truncated (residual exactly absorbed by next term), l RNE
__device__ __forceinline__ void split3t(float f, ushort& h, ushort& m, ushort& l) {
  h = (ushort)(__float_as_uint(f) >> 16);
  float r  = f - bf2f(h);
  m = (ushort)(__float_as_uint(r) >> 16);
  float r2 = r - bf2f(m);
  l = f2bf(r2);
}

// ---------------------------------------------------------------------------
// Prologue: bias gather + all weight splits, computed ONCE (not per block).
// tasks: [0,131072) bias_g | +16384 wq | +16384 wk | +16384 wv | +16384 wpt
// ---------------------------------------------------------------------------
__global__ __launch_bounds__(512)
void prep_kernel(const int* __restrict__ rel_index, const float* __restrict__ table,
                 const float* __restrict__ Wq, const float* __restrict__ Wkv,
                 const float* __restrict__ Wproj, char* __restrict__ ws) {
  float*  bias_g = (float*)(ws + BIAS_OFF);
  ushort* wq_g   = (ushort*)(ws + WQ_OFF);
  ushort* wk_g   = (ushort*)(ws + WK_OFF);
  ushort* wv_g   = (ushort*)(ws + WV_OFF);
  ushort* wpt_g  = (ushort*)(ws + WPT_OFF);

  int idx = blockIdx.x * 512 + threadIdx.x;
  if (idx < 131072) {
    int h = idx >> 14, mn = idx & 16383;
    bias_g[idx] = table[rel_index[mn] * NHEAD + h];
  } else if (idx < 131072 + 16384) {
    int t = idx - 131072;                 // h*2048 + oc*128 + kk
    int h = t >> 11, r = t & 2047, oc = r >> 7, kk = r & 127;
    ushort a, bb, cc;
    split3(Wq[kk * C_DIM + h * 16 + oc] * 0.25f, a, bb, cc);
    wq_g[(h * 3 + 0) * 2048 + oc * 128 + kk] = a;
    wq_g[(h * 3 + 1) * 2048 + oc * 128 + kk] = bb;
    wq_g[(h * 3 + 2) * 2048 + oc * 128 + kk] = cc;
  } else if (idx < 131072 + 2 * 16384) {
    int t = idx - 131072 - 16384;
    int h = t >> 11, r = t & 2047, oc = r >> 7, kk = r & 127;
    ushort a, bb, cc;
    split3(Wkv[kk * (2 * C_DIM) + h * 16 + oc], a, bb, cc);
    wk_g[(h * 3 + 0) * 2048 + oc * 128 + kk] = a;
    wk_g[(h * 3 + 1) * 2048 + oc * 128 + kk] = bb;
    wk_g[(h * 3 + 2) * 2048 + oc * 128 + kk] = cc;
  } else if (idx < 131072 + 3 * 16384) {
    int t = idx - 131072 - 2 * 16384;
    int h = t >> 11, r = t & 2047, oc = r >> 7, kk = r & 127;
    wv_g[h * 2048 + oc * 128 + kk] = f2bf(Wkv[kk * (2 * C_DIM) + C_DIM + h * 16 + oc]);
  } else if (idx < 131072 + 4 * 16384) {
    int t = idx - 131072 - 3 * 16384;     // hp*4096 + n*32 + kk
    int hp = t >> 12, r = t & 4095, n = r >> 5, kk = r & 31;
    wpt_g[t] = f2bf(Wproj[(hp * 32 + kk) * C_DIM + n]);
  }
}

// ---------------------------------------------------------------------------
// Fused window attention. 512 threads = 8 waves; wave w owns rows 16w..16w+15.
// LDS (47616 B -> 2 blocks/CU):
//   qs @0      [128][56] bf16  [qh|qm|ql]   14336
//   ks @14336  [128][56] bf16  [kh|km|kl]   14336
//   vs @28672  [128][17] fp32  v             8704
//   xo @37376  [128][40] bf16  attn out     10240
// x rows and all W fragments are read from global (L1/L2-resident).
// ---------------------------------------------------------------------------
__global__ __launch_bounds__(512, 4)
void wattn_kernel(const float* __restrict__ x, const float* __restrict__ mask,
                  const float* __restrict__ bproj, const char* __restrict__ ws,
                  float* __restrict__ out) {
  extern __shared__ char smem[];
  ushort* qs = (ushort*)(smem);
  ushort* ks = (ushort*)(smem + 14336);
  float*  vs = (float*)(smem + 28672);
  ushort* xo = (ushort*)(smem + 37376);

  const float*  bias_g = (const float*)(ws + BIAS_OFF);
  const ushort* wq_g   = (const ushort*)(ws + WQ_OFF);
  const ushort* wk_g   = (const ushort*)(ws + WK_OFF);
  const ushort* wv_g   = (const ushort*)(ws + WV_OFF);
  const ushort* wpt_g  = (const ushort*)(ws + WPT_OFF);

  const int tid  = threadIdx.x;
  const int w    = tid >> 6;
  const int l    = tid & 63;
  const int quad = l >> 4;
  const int c    = l & 15;
  const int b    = blockIdx.x;
  const int wi   = b & (NW_MASK - 1);

  const float* xrow = x + ((size_t)b * N_TOK + 16 * w + c) * C_DIM;

  floatx4 oacc[8];
  #pragma unroll
  for (int j = 0; j < 8; ++j) oacc[j] = (floatx4){0.f, 0.f, 0.f, 0.f};

  for (int h = 0; h < NHEAD; ++h) {
    // ---- phase 2: q,k (6-term split) and v (2-term) projections
    {
      floatx4 aq = (floatx4){0.f,0.f,0.f,0.f};
      floatx4 ak = (floatx4){0.f,0.f,0.f,0.f};
      floatx4 av = (floatx4){0.f,0.f,0.f,0.f};
      const ushort* wqp = wq_g + h * 3 * 2048 + c * 128;
      const ushort* wkp = wk_g + h * 3 * 2048 + c * 128;
      const ushort* wvp = wv_g + h * 2048 + c * 128;
      const int q3off = (quad < 2) ? 4096 : 0;   // wql for xh-lanes, wqh for xl-lanes
      #pragma unroll
      for (int kt = 0; kt < 8; ++kt) {
        int colb = kt * 16 + (quad & 1) * 8;
        floatx4 xa  = *(const floatx4*)(xrow + colb);
        floatx4 xb2 = *(const floatx4*)(xrow + colb + 4);
        short8 hi8, mi8, lo8;
        #pragma unroll
        for (int jj = 0; jj < 8; ++jj) {
          float f = (jj < 4) ? xa[jj] : xb2[jj - 4];
          ushort hh, mm, ll; split3t(f, hh, mm, ll);
          hi8[jj] = (short)hh; mi8[jj] = (short)mm; lo8[jj] = (short)ll;
        }
        short8 a1 = (quad < 2) ? hi8 : mi8;   // [xh|xm]
        short8 a3 = (quad < 2) ? hi8 : lo8;   // [xh|xl]
        short8 bq1 = *(const short8*)(wqp + colb);
        short8 bq2 = *(const short8*)(wqp + 2048 + colb);
        short8 bq3 = *(const short8*)(wqp + q3off + colb);
        aq = MFMA(a1, bq1, aq);  aq = MFMA(a1, bq2, aq);  aq = MFMA(a3, bq3, aq);
        short8 bk1 = *(const short8*)(wkp + colb);
        short8 bk2 = *(const short8*)(wkp + 2048 + colb);
        short8 bk3 = *(const short8*)(wkp + q3off + colb);
        ak = MFMA(a1, bk1, ak);  ak = MFMA(a1, bk2, ak);  ak = MFMA(a3, bk3, ak);
        short8 bv1 = *(const short8*)(wvp + colb);
        av = MFMA(a1, bv1, av);
      }
      #pragma unroll
      for (int i = 0; i < 4; ++i) {
        int tok = 16 * w + 4 * quad + i;
        ushort a, bb, cc;
        split3t(aq[i], a, bb, cc);
        qs[tok * 56 + c] = a; qs[tok * 56 + 16 + c] = bb; qs[tok * 56 + 32 + c] = cc;
        split3t(ak[i], a, bb, cc);
        ks[tok * 56 + c] = a; ks[tok * 56 + 16 + c] = bb; ks[tok * 56 + 32 + c] = cc;
        vs[tok * 17 + c] = av[i];
      }
    }
    __syncthreads();

    // ---- phase 3: logits S = q.k^T (6 split terms) + bias + mask (fp32 init)
    floatx4 sacc[8];
    {
      const ushort* qrow = qs + (16 * w + c) * 56;
      short8 aq1 = *(const short8*)(qrow + quad * 8);                      // [qh|qm]
      short8 aq3 = *(const short8*)(qrow + ((quad < 2) ? quad * 8 : 16 + quad * 8)); // [qh|ql]
      #pragma unroll
      for (int j = 0; j < 8; ++j) {
        floatx4 acc;
        #pragma unroll
        for (int i = 0; i < 4; ++i) {
          int m = 16 * w + 4 * quad + i;
          int n = 16 * j + c;
          acc[i] = bias_g[(h * N_TOK + m) * N_TOK + n] +
                   mask[(wi * N_TOK + m) * N_TOK + n];
        }
        const ushort* krow = ks + (16 * j + c) * 56;
        int bo1 = (quad & 1) * 8;
        short8 b1 = *(const short8*)(krow + bo1);            // [kh|kh]
        short8 b2 = *(const short8*)(krow + 16 + bo1);       // [km|km]
        short8 b3 = *(const short8*)(krow + ((quad < 2) ? 32 + quad * 8
                                                        : (quad - 2) * 8)); // [kl|kh]
        acc = MFMA(aq1, b1, acc);
        acc = MFMA(aq1, b2, acc);
        acc = MFMA(aq3, b3, acc);
        sacc[j] = acc;
      }
    }

    // ---- phase 3b: register softmax denom + top-2, weighted V gather
    #pragma unroll
    for (int i = 0; i < 4; ++i) {
      float m1 = sacc[0][i]; int i1 = c;
      float m2 = -__builtin_inff(); int i2 = -1;
      float psum = 1.0f;
      #pragma unroll
      for (int j = 1; j < 8; ++j) {
        float v = sacc[j][i]; int col = 16 * j + c;
        bool g1 = v > m1;
        float e = __expf(g1 ? (m1 - v) : (v - m1));
        psum = g1 ? (psum * e + 1.0f) : (psum + e);
        bool g2 = (!g1) && (v > m2);
        m2 = g1 ? m1 : (g2 ? v : m2);
        i2 = g1 ? i1 : (g2 ? col : i2);
        m1 = g1 ? v : m1;
        i1 = g1 ? col : i1;
      }
      #pragma unroll
      for (int d = 1; d < 16; d <<= 1) {
        float om1 = __shfl_xor(m1, d); int oi1 = __shfl_xor(i1, d);
        float om2 = __shfl_xor(m2, d); int oi2 = __shfl_xor(i2, d);
        float ops = __shfl_xor(psum, d);
        bool aw = (m1 > om1) || (m1 == om1 && i1 < oi1);
        float M  = aw ? m1 : om1;  int I  = aw ? i1 : oi1;
        float lv = aw ? om1 : m1;  int li = aw ? oi1 : i1;
        float sv = aw ? m2 : om2;  int si = aw ? i2 : oi2;
        bool sb = (sv > lv) || (sv == lv && si < li);
        float e = __expf(lv - M);
        psum = (aw ? psum : ops) + (aw ? ops : psum) * e;
        m1 = M; i1 = I;
        m2 = sb ? sv : lv; i2 = sb ? si : li;
      }
      float p1 = 1.0f / psum;
      float p2 = __expf(m2 - m1) * p1;
      int tok = 16 * w + 4 * quad + i;
      float o = p1 * vs[i1 * 17 + c] + p2 * vs[i2 * 17 + c];
      xo[tok * 40 + (h & 1) * 16 + c] = f2bf(o);
    }

    // ---- phase 4: out-projection, K=32 per head pair, persistent acc
    if (h & 1) {
      const ushort* wptp = wpt_g + (size_t)(h >> 1) * 4096;
      short8 a = *(const short8*)(xo + (16 * w + c) * 40 + quad * 8);
      #pragma unroll
      for (int j = 0; j < 8; ++j) {
        short8 bf = *(const short8*)(wptp + (16 * j + c) * 32 + quad * 8);
        oacc[j] = MFMA(a, bf, oacc[j]);
      }
    }
    __syncthreads();
  }

  // ---- epilogue: + bproj, fp32 store
  #pragma unroll
  for (int j = 0; j < 8; ++j) {
    float bp = bproj[16 * j + c];
    #pragma unroll
    for (int i = 0; i < 4; ++i) {
      int row = 16 * w + 4 * quad + i;
      out[((size_t)b * N_TOK + row) * C_DIM + 16 * j + c] = oacc[j][i] + bp;
    }
  }
}

extern "C" void kernel_launch(void* const* d_in, const int* in_sizes, int n_in,
                              void* d_out, int out_size, void* d_ws, size_t ws_size,
                              hipStream_t stream) {
  const float* x     = (const float*)d_in[0];
  const float* mask  = (const float*)d_in[1];
  const float* Wq    = (const float*)d_in[2];
  const float* Wkv   = (const float*)d_in[3];
  const float* Wproj = (const float*)d_in[4];
  const float* bproj = (const float*)d_in[5];
  const float* btab  = (const float*)d_in[6];
  const int*   ridx  = (const int*)d_in[7];
  float* outp = (float*)d_out;
  char*  ws   = (char*)d_ws;

  (void)in_sizes; (void)n_in; (void)out_size; (void)ws_size;

  hipFuncSetAttribute(reinterpret_cast<const void*>(wattn_kernel),
                      hipFuncAttributeMaxDynamicSharedMemorySize, 47616);

  // 131072 bias + 4*16384 weight-split tasks = 196608 -> 384 blocks
  prep_kernel<<<384, 512, 0, stream>>>(ridx, btab, Wq, Wkv, Wproj, ws);
  wattn_kernel<<<B_TOT, 512, 47616, stream>>>(x, mask, bproj, ws, outp);
}

// Round 2
// 716.218 us; speedup vs baseline: 1.1811x; 1.1811x over previous
//
#include <hip/hip_runtime.h>
#include <hip/hip_bf16.h>
#include <stdint.h>

typedef __attribute__((ext_vector_type(8))) short short8;
typedef __attribute__((ext_vector_type(4))) float floatx4;

#define B_TOT 1024
#define N_TOK 128
#define C_DIM 128
#define NHEAD 8
#define NW_MASK 64

// ---- workspace layout (bytes) ----
#define BIAS_OFF 0         // [8][128][128] fp32                     524288
#define WQ_OFF   524288    // [8h][3p][16oc][128kk] ushort            98304
#define WK_OFF   622592    // [8h][3p][16oc][128kk] ushort            98304
#define WV_OFF   720896    // [8h][16oc][128kk] ushort                32768
#define WPT_OFF  753664    // [4hp][128n][32kk] ushort                32768
#define WS_BYTES 786432

#define MFMA(a, b, c) __builtin_amdgcn_mfma_f32_16x16x32_bf16((a), (b), (c), 0, 0, 0)

__device__ __forceinline__ float bf2f(ushort u) {
  union { uint32_t u; float f; } v; v.u = ((uint32_t)u) << 16; return v.f;
}
__device__ __forceinline__ ushort f2bf(float f) {
  uint32_t u = __float_as_uint(f);
  return (ushort)((u + 0x7FFFu + ((u >> 16) & 1u)) >> 16);  // RNE
}
// full-RNE 3-way split (used once, in prep)
__device__ __forceinline__ void split3(float f, ushort& h, ushort& m, ushort& l) {
  h = f2bf(f);  float r  = f - bf2f(h);
  m = f2bf(r);  float r2 = r - bf2f(m);
  l = f2bf(r2);
}
// cheap split: h,m truncated (residual exactly absorbed by next term), l RNE
__device__ __forceinline__ void split3t(float f, ushort& h, ushort& m, ushort& l) {
  h = (ushort)(__float_as_uint(f) >> 16);
  float r  = f - bf2f(h);
  m = (ushort)(__float_as_uint(r) >> 16);
  float r2 = r - bf2f(m);
  l = f2bf(r2);
}

// ---------------------------------------------------------------------------
// Prologue: bias gather + all weight splits, computed ONCE (not per block).
// tasks: [0,131072) bias_g | +16384 wq | +16384 wk | +16384 wv | +16384 wpt
// ---------------------------------------------------------------------------
__global__ __launch_bounds__(512)
void prep_kernel(const int* __restrict__ rel_index, const float* __restrict__ table,
                 const float* __restrict__ Wq, const float* __restrict__ Wkv,
                 const float* __restrict__ Wproj, char* __restrict__ ws) {
  float*  bias_g = (float*)(ws + BIAS_OFF);
  ushort* wq_g   = (ushort*)(ws + WQ_OFF);
  ushort* wk_g   = (ushort*)(ws + WK_OFF);
  ushort* wv_g   = (ushort*)(ws + WV_OFF);
  ushort* wpt_g  = (ushort*)(ws + WPT_OFF);

  int idx = blockIdx.x * 512 + threadIdx.x;
  if (idx < 131072) {
    int h = idx >> 14, mn = idx & 16383;
    bias_g[idx] = table[rel_index[mn] * NHEAD + h];
  } else if (idx < 131072 + 16384) {
    int t = idx - 131072;                 // h*2048 + oc*128 + kk
    int h = t >> 11, r = t & 2047, oc = r >> 7, kk = r & 127;
    ushort a, bb, cc;
    split3(Wq[kk * C_DIM + h * 16 + oc] * 0.25f, a, bb, cc);
    wq_g[(h * 3 + 0) * 2048 + oc * 128 + kk] = a;
    wq_g[(h * 3 + 1) * 2048 + oc * 128 + kk] = bb;
    wq_g[(h * 3 + 2) * 2048 + oc * 128 + kk] = cc;
  } else if (idx < 131072 + 2 * 16384) {
    int t = idx - 131072 - 16384;
    int h = t >> 11, r = t & 2047, oc = r >> 7, kk = r & 127;
    ushort a, bb, cc;
    split3(Wkv[kk * (2 * C_DIM) + h * 16 + oc], a, bb, cc);
    wk_g[(h * 3 + 0) * 2048 + oc * 128 + kk] = a;
    wk_g[(h * 3 + 1) * 2048 + oc * 128 + kk] = bb;
    wk_g[(h * 3 + 2) * 2048 + oc * 128 + kk] = cc;
  } else if (idx < 131072 + 3 * 16384) {
    int t = idx - 131072 - 2 * 16384;
    int h = t >> 11, r = t & 2047, oc = r >> 7, kk = r & 127;
    wv_g[h * 2048 + oc * 128 + kk] = f2bf(Wkv[kk * (2 * C_DIM) + C_DIM + h * 16 + oc]);
  } else if (idx < 131072 + 4 * 16384) {
    int t = idx - 131072 - 3 * 16384;     // hp*4096 + n*32 + kk
    int hp = t >> 12, r = t & 4095, n = r >> 5, kk = r & 31;
    wpt_g[t] = f2bf(Wproj[(hp * 32 + kk) * C_DIM + n]);
  }
}

// ---------------------------------------------------------------------------
// Fused window attention. 512 threads = 8 waves; wave w owns rows 16w..16w+15.
// LDS (47616 B -> 2 blocks/CU @ VGPR<=128):
//   qs @0      [128][56] bf16  [qh|qm|ql]   14336
//   ks @14336  [128][56] bf16  [kh|km|kl]   14336
//   vs @28672  [128][17] fp32  v             8704
//   xo @37376  [128][40] bf16  attn out     10240
// x rows and all W fragments are read from global (L1/L2/L3-resident).
// Phase 3 (logits) and 3b (softmax/top-2) are FUSED so no sacc[8] array is
// ever live -> peak VGPR ~90, no spill at the 128 cap.
// ---------------------------------------------------------------------------
__global__ __launch_bounds__(512, 2)
void wattn_kernel(const float* __restrict__ x, const float* __restrict__ mask,
                  const float* __restrict__ bproj, const char* __restrict__ ws,
                  float* __restrict__ out) {
  extern __shared__ char smem[];
  ushort* qs = (ushort*)(smem);
  ushort* ks = (ushort*)(smem + 14336);
  float*  vs = (float*)(smem + 28672);
  ushort* xo = (ushort*)(smem + 37376);

  const float*  bias_g = (const float*)(ws + BIAS_OFF);
  const ushort* wq_g   = (const ushort*)(ws + WQ_OFF);
  const ushort* wk_g   = (const ushort*)(ws + WK_OFF);
  const ushort* wv_g   = (const ushort*)(ws + WV_OFF);
  const ushort* wpt_g  = (const ushort*)(ws + WPT_OFF);

  const int tid  = threadIdx.x;
  const int w    = tid >> 6;
  const int l    = tid & 63;
  const int quad = l >> 4;
  const int c    = l & 15;
  const int b    = blockIdx.x;
  const int wi   = b & (NW_MASK - 1);

  const float* xrow = x + ((size_t)b * N_TOK + 16 * w + c) * C_DIM;

  floatx4 oacc[8];
  #pragma unroll
  for (int j = 0; j < 8; ++j) oacc[j] = (floatx4){0.f, 0.f, 0.f, 0.f};

  for (int h = 0; h < NHEAD; ++h) {
    // ---- phase 2: q,k (6-term split) and v (2-term) projections
    {
      floatx4 aq = (floatx4){0.f,0.f,0.f,0.f};
      floatx4 ak = (floatx4){0.f,0.f,0.f,0.f};
      floatx4 av = (floatx4){0.f,0.f,0.f,0.f};
      const ushort* wqp = wq_g + h * 3 * 2048 + c * 128;
      const ushort* wkp = wk_g + h * 3 * 2048 + c * 128;
      const ushort* wvp = wv_g + h * 2048 + c * 128;
      const int q3off = (quad < 2) ? 4096 : 0;   // wql for xh-lanes, wqh for xl-lanes
      #pragma unroll
      for (int kt = 0; kt < 8; ++kt) {
        int colb = kt * 16 + (quad & 1) * 8;
        floatx4 xa  = *(const floatx4*)(xrow + colb);
        floatx4 xb2 = *(const floatx4*)(xrow + colb + 4);
        short8 hi8, mi8, lo8;
        #pragma unroll
        for (int jj = 0; jj < 8; ++jj) {
          float f = (jj < 4) ? xa[jj] : xb2[jj - 4];
          ushort hh, mm, ll; split3t(f, hh, mm, ll);
          hi8[jj] = (short)hh; mi8[jj] = (short)mm; lo8[jj] = (short)ll;
        }
        short8 a1 = (quad < 2) ? hi8 : mi8;   // [xh|xm]
        short8 a3 = (quad < 2) ? hi8 : lo8;   // [xh|xl]
        short8 bq1 = *(const short8*)(wqp + colb);
        short8 bq2 = *(const short8*)(wqp + 2048 + colb);
        short8 bq3 = *(const short8*)(wqp + q3off + colb);
        aq = MFMA(a1, bq1, aq);  aq = MFMA(a1, bq2, aq);  aq = MFMA(a3, bq3, aq);
        short8 bk1 = *(const short8*)(wkp + colb);
        short8 bk2 = *(const short8*)(wkp + 2048 + colb);
        short8 bk3 = *(const short8*)(wkp + q3off + colb);
        ak = MFMA(a1, bk1, ak);  ak = MFMA(a1, bk2, ak);  ak = MFMA(a3, bk3, ak);
        short8 bv1 = *(const short8*)(wvp + colb);
        av = MFMA(a1, bv1, av);
      }
      #pragma unroll
      for (int i = 0; i < 4; ++i) {
        int tok = 16 * w + 4 * quad + i;
        ushort a, bb, cc;
        split3t(aq[i], a, bb, cc);
        qs[tok * 56 + c] = a; qs[tok * 56 + 16 + c] = bb; qs[tok * 56 + 32 + c] = cc;
        split3t(ak[i], a, bb, cc);
        ks[tok * 56 + c] = a; ks[tok * 56 + 16 + c] = bb; ks[tok * 56 + 32 + c] = cc;
        vs[tok * 17 + c] = av[i];
      }
    }
    __syncthreads();

    // ---- phase 3 (fused): logits j-tile -> immediate softmax/top-2 fold
    {
      const ushort* qrow = qs + (16 * w + c) * 56;
      short8 aq1 = *(const short8*)(qrow + quad * 8);                      // [qh|qm]
      short8 aq3 = *(const short8*)(qrow + ((quad < 2) ? quad * 8 : 16 + quad * 8)); // [qh|ql]

      float m1[4], m2[4], psum[4];
      int   i1[4], i2[4];

      #pragma unroll
      for (int j = 0; j < 8; ++j) {
        floatx4 acc;
        #pragma unroll
        for (int i = 0; i < 4; ++i) {
          int m = 16 * w + 4 * quad + i;
          int n = 16 * j + c;
          acc[i] = bias_g[(h * N_TOK + m) * N_TOK + n] +
                   mask[(wi * N_TOK + m) * N_TOK + n];
        }
        const ushort* krow = ks + (16 * j + c) * 56;
        int bo1 = (quad & 1) * 8;
        short8 b1 = *(const short8*)(krow + bo1);            // [kh|kh]
        short8 b2 = *(const short8*)(krow + 16 + bo1);       // [km|km]
        short8 b3 = *(const short8*)(krow + ((quad < 2) ? 32 + quad * 8
                                                        : (quad - 2) * 8)); // [kl|kh]
        acc = MFMA(aq1, b1, acc);
        acc = MFMA(aq1, b2, acc);
        acc = MFMA(aq3, b3, acc);

        if (j == 0) {
          #pragma unroll
          for (int i = 0; i < 4; ++i) {
            m1[i] = acc[i]; i1[i] = c;
            m2[i] = -__builtin_inff(); i2[i] = -1;
            psum[i] = 1.0f;
          }
        } else {
          #pragma unroll
          for (int i = 0; i < 4; ++i) {
            float v = acc[i]; int col = 16 * j + c;
            bool g1 = v > m1[i];
            float e = __expf(g1 ? (m1[i] - v) : (v - m1[i]));
            psum[i] = g1 ? (psum[i] * e + 1.0f) : (psum[i] + e);
            bool g2 = (!g1) && (v > m2[i]);
            m2[i] = g1 ? m1[i] : (g2 ? v : m2[i]);
            i2[i] = g1 ? i1[i] : (g2 ? col : i2[i]);
            m1[i] = g1 ? v : m1[i];
            i1[i] = g1 ? col : i1[i];
          }
        }
      }

      // ---- cross-lane reduce over the 16 columns held by the quad's lanes
      #pragma unroll
      for (int i = 0; i < 4; ++i) {
        float M1 = m1[i], M2 = m2[i], PS = psum[i];
        int I1 = i1[i], I2 = i2[i];
        #pragma unroll
        for (int d = 1; d < 16; d <<= 1) {
          float om1 = __shfl_xor(M1, d); int oi1 = __shfl_xor(I1, d);
          float om2 = __shfl_xor(M2, d); int oi2 = __shfl_xor(I2, d);
          float ops = __shfl_xor(PS, d);
          bool aw = (M1 > om1) || (M1 == om1 && I1 < oi1);
          float M  = aw ? M1 : om1;  int I  = aw ? I1 : oi1;
          float lv = aw ? om1 : M1;  int li = aw ? oi1 : I1;
          float sv = aw ? M2 : om2;  int si = aw ? I2 : oi2;
          bool sb = (sv > lv) || (sv == lv && si < li);
          float e = __expf(lv - M);
          PS = (aw ? PS : ops) + (aw ? ops : PS) * e;
          M1 = M; I1 = I;
          M2 = sb ? sv : lv; I2 = sb ? si : li;
        }
        float p1 = 1.0f / PS;
        float p2 = __expf(M2 - M1) * p1;
        int tok = 16 * w + 4 * quad + i;
        float o = p1 * vs[I1 * 17 + c] + p2 * vs[I2 * 17 + c];
        xo[tok * 40 + (h & 1) * 16 + c] = f2bf(o);
      }
    }

    // ---- phase 4: out-projection, K=32 per head pair, persistent acc
    if (h & 1) {
      const ushort* wptp = wpt_g + (size_t)(h >> 1) * 4096;
      short8 a = *(const short8*)(xo + (16 * w + c) * 40 + quad * 8);
      #pragma unroll
      for (int j = 0; j < 8; ++j) {
        short8 bf = *(const short8*)(wptp + (16 * j + c) * 32 + quad * 8);
        oacc[j] = MFMA(a, bf, oacc[j]);
      }
    }
    __syncthreads();
  }

  // ---- epilogue: + bproj, fp32 store
  #pragma unroll
  for (int j = 0; j < 8; ++j) {
    float bp = bproj[16 * j + c];
    #pragma unroll
    for (int i = 0; i < 4; ++i) {
      int row = 16 * w + 4 * quad + i;
      out[((size_t)b * N_TOK + row) * C_DIM + 16 * j + c] = oacc[j][i] + bp;
    }
  }
}

extern "C" void kernel_launch(void* const* d_in, const int* in_sizes, int n_in,
                              void* d_out, int out_size, void* d_ws, size_t ws_size,
                              hipStream_t stream) {
  const float* x     = (const float*)d_in[0];
  const float* mask  = (const float*)d_in[1];
  const float* Wq    = (const float*)d_in[2];
  const float* Wkv   = (const float*)d_in[3];
  const float* Wproj = (const float*)d_in[4];
  const float* bproj = (const float*)d_in[5];
  const float* btab  = (const float*)d_in[6];
  const int*   ridx  = (const int*)d_in[7];
  float* outp = (float*)d_out;
  char*  ws   = (char*)d_ws;

  (void)in_sizes; (void)n_in; (void)out_size; (void)ws_size;

  hipFuncSetAttribute(reinterpret_cast<const void*>(wattn_kernel),
                      hipFuncAttributeMaxDynamicSharedMemorySize, 47616);

  // 131072 bias + 4*16384 weight-split tasks = 196608 -> 384 blocks
  prep_kernel<<<384, 512, 0, stream>>>(ridx, btab, Wq, Wkv, Wproj, ws);
  wattn_kernel<<<B_TOT, 512, 47616, stream>>>(x, mask, bproj, ws, outp);
}

// Round 3
// 715.790 us; speedup vs baseline: 1.1818x; 1.0006x over previous
//
#include <hip/hip_runtime.h>
#include <hip/hip_bf16.h>
#include <stdint.h>

typedef __attribute__((ext_vector_type(8))) short short8;
typedef __attribute__((ext_vector_type(4))) float floatx4;

#define B_TOT 1024
#define N_TOK 128
#define C_DIM 128
#define NHEAD 8
#define NW_MASK 64

// ---- workspace layout (bytes) ----
#define BIAS_OFF 0         // [8][128][128] fp32                     524288
#define WQ_OFF   524288    // [8h][3p][16oc][128kk] ushort            98304
#define WK_OFF   622592    // [8h][3p][16oc][128kk] ushort            98304
#define WV_OFF   720896    // [8h][16oc][128kk] ushort                32768
#define WPT_OFF  753664    // [4hp][128n][32kk] ushort                32768
#define WS_BYTES 786432

#define MFMA(a, b, c) __builtin_amdgcn_mfma_f32_16x16x32_bf16((a), (b), (c), 0, 0, 0)

__device__ __forceinline__ float bf2f(ushort u) {
  union { uint32_t u; float f; } v; v.u = ((uint32_t)u) << 16; return v.f;
}
__device__ __forceinline__ ushort f2bf(float f) {
  uint32_t u = __float_as_uint(f);
  return (ushort)((u + 0x7FFFu + ((u >> 16) & 1u)) >> 16);  // RNE
}
// full-RNE 3-way split (used once, in prep)
__device__ __forceinline__ void split3(float f, ushort& h, ushort& m, ushort& l) {
  h = f2bf(f);  float r  = f - bf2f(h);
  m = f2bf(r);  float r2 = r - bf2f(m);
  l = f2bf(r2);
}
// cheap split: h,m truncated (residual exactly absorbed by next term), l RNE
__device__ __forceinline__ void split3t(float f, ushort& h, ushort& m, ushort& l) {
  h = (ushort)(__float_as_uint(f) >> 16);
  float r  = f - bf2f(h);
  m = (ushort)(__float_as_uint(r) >> 16);
  float r2 = r - bf2f(m);
  l = f2bf(r2);
}

// ---------------------------------------------------------------------------
// Prologue: bias gather + all weight splits, computed ONCE (not per block).
// tasks: [0,131072) bias_g | +16384 wq | +16384 wk | +16384 wv | +16384 wpt
// ---------------------------------------------------------------------------
__global__ __launch_bounds__(512)
void prep_kernel(const int* __restrict__ rel_index, const float* __restrict__ table,
                 const float* __restrict__ Wq, const float* __restrict__ Wkv,
                 const float* __restrict__ Wproj, char* __restrict__ ws) {
  float*  bias_g = (float*)(ws + BIAS_OFF);
  ushort* wq_g   = (ushort*)(ws + WQ_OFF);
  ushort* wk_g   = (ushort*)(ws + WK_OFF);
  ushort* wv_g   = (ushort*)(ws + WV_OFF);
  ushort* wpt_g  = (ushort*)(ws + WPT_OFF);

  int idx = blockIdx.x * 512 + threadIdx.x;
  if (idx < 131072) {
    int h = idx >> 14, mn = idx & 16383;
    bias_g[idx] = table[rel_index[mn] * NHEAD + h];
  } else if (idx < 131072 + 16384) {
    int t = idx - 131072;                 // h*2048 + oc*128 + kk
    int h = t >> 11, r = t & 2047, oc = r >> 7, kk = r & 127;
    ushort a, bb, cc;
    split3(Wq[kk * C_DIM + h * 16 + oc] * 0.25f, a, bb, cc);
    wq_g[(h * 3 + 0) * 2048 + oc * 128 + kk] = a;
    wq_g[(h * 3 + 1) * 2048 + oc * 128 + kk] = bb;
    wq_g[(h * 3 + 2) * 2048 + oc * 128 + kk] = cc;
  } else if (idx < 131072 + 2 * 16384) {
    int t = idx - 131072 - 16384;
    int h = t >> 11, r = t & 2047, oc = r >> 7, kk = r & 127;
    ushort a, bb, cc;
    split3(Wkv[kk * (2 * C_DIM) + h * 16 + oc], a, bb, cc);
    wk_g[(h * 3 + 0) * 2048 + oc * 128 + kk] = a;
    wk_g[(h * 3 + 1) * 2048 + oc * 128 + kk] = bb;
    wk_g[(h * 3 + 2) * 2048 + oc * 128 + kk] = cc;
  } else if (idx < 131072 + 3 * 16384) {
    int t = idx - 131072 - 2 * 16384;
    int h = t >> 11, r = t & 2047, oc = r >> 7, kk = r & 127;
    wv_g[h * 2048 + oc * 128 + kk] = f2bf(Wkv[kk * (2 * C_DIM) + C_DIM + h * 16 + oc]);
  } else if (idx < 131072 + 4 * 16384) {
    int t = idx - 131072 - 3 * 16384;     // hp*4096 + n*32 + kk
    int hp = t >> 12, r = t & 4095, n = r >> 5, kk = r & 31;
    wpt_g[t] = f2bf(Wproj[(hp * 32 + kk) * C_DIM + n]);
  }
}

// ---------------------------------------------------------------------------
// Fused window attention. 512 threads = 8 waves; wave w owns rows 16w..16w+15.
// KEY CHANGE vs round 2: the per-lane x MFMA A-fragments are HEAD-INVARIANT,
// so they are split ONCE per block into 32 VGPRs (A1[8],A3[8]) and reused for
// all 8 heads. Phase 2 is then pure {independent L1-hot B loads -> MFMA}.
// LDS (47616 B):
//   qs @0      [128][56] bf16  [qh|qm|ql]   14336
//   ks @14336  [128][56] bf16  [kh|km|kl]   14336
//   vs @28672  [128][17] fp32  v             8704
//   xo @37376  [128][40] bf16  attn out     10240
// ---------------------------------------------------------------------------
__global__ __launch_bounds__(512, 2)
void wattn_kernel(const float* __restrict__ x, const float* __restrict__ mask,
                  const float* __restrict__ bproj, const char* __restrict__ ws,
                  float* __restrict__ out) {
  extern __shared__ char smem[];
  ushort* qs = (ushort*)(smem);
  ushort* ks = (ushort*)(smem + 14336);
  float*  vs = (float*)(smem + 28672);
  ushort* xo = (ushort*)(smem + 37376);

  const float*  bias_g = (const float*)(ws + BIAS_OFF);
  const ushort* wq_g   = (const ushort*)(ws + WQ_OFF);
  const ushort* wk_g   = (const ushort*)(ws + WK_OFF);
  const ushort* wv_g   = (const ushort*)(ws + WV_OFF);
  const ushort* wpt_g  = (const ushort*)(ws + WPT_OFF);

  const int tid  = threadIdx.x;
  const int w    = tid >> 6;
  const int l    = tid & 63;
  const int quad = l >> 4;
  const int c    = l & 15;
  const int b    = blockIdx.x;
  const int wi   = b & (NW_MASK - 1);

  // ---- block prologue: split this lane's x fragments ONCE into registers.
  // A1[kt] = (quad<2 ? xh : xm) row (16w+c), cols kt*16+(quad&1)*8 .. +8
  // A3[kt] = (quad<2 ? xh : xl) same cols
  short8 A1[8], A3[8];
  {
    const float* xrow = x + ((size_t)b * N_TOK + 16 * w + c) * C_DIM;
    #pragma unroll
    for (int kt = 0; kt < 8; ++kt) {
      int colb = kt * 16 + (quad & 1) * 8;
      floatx4 xa  = *(const floatx4*)(xrow + colb);
      floatx4 xb2 = *(const floatx4*)(xrow + colb + 4);
      short8 hi8, mi8, lo8;
      #pragma unroll
      for (int jj = 0; jj < 8; ++jj) {
        float f = (jj < 4) ? xa[jj] : xb2[jj - 4];
        ushort hh, mm, ll; split3t(f, hh, mm, ll);
        hi8[jj] = (short)hh; mi8[jj] = (short)mm; lo8[jj] = (short)ll;
      }
      A1[kt] = (quad < 2) ? hi8 : mi8;   // [xh|xm]
      A3[kt] = (quad < 2) ? hi8 : lo8;   // [xh|xl]
    }
  }

  floatx4 oacc[8];
  #pragma unroll
  for (int j = 0; j < 8; ++j) oacc[j] = (floatx4){0.f, 0.f, 0.f, 0.f};

  for (int h = 0; h < NHEAD; ++h) {
    // ---- phase 2: q,k (6-term split) and v (2-term) projections.
    // A operands from registers; B operands from presplit global (L1-hot 28KB).
    {
      floatx4 aq = (floatx4){0.f,0.f,0.f,0.f};
      floatx4 ak = (floatx4){0.f,0.f,0.f,0.f};
      floatx4 av = (floatx4){0.f,0.f,0.f,0.f};
      const ushort* wqp = wq_g + h * 3 * 2048 + c * 128;
      const ushort* wkp = wk_g + h * 3 * 2048 + c * 128;
      const ushort* wvp = wv_g + h * 2048 + c * 128;
      const int q3off = (quad < 2) ? 4096 : 0;   // wql for xh-lanes, wqh for xl-lanes
      #pragma unroll
      for (int kt = 0; kt < 8; ++kt) {
        int colb = kt * 16 + (quad & 1) * 8;
        short8 bq1 = *(const short8*)(wqp + colb);
        short8 bq2 = *(const short8*)(wqp + 2048 + colb);
        short8 bq3 = *(const short8*)(wqp + q3off + colb);
        aq = MFMA(A1[kt], bq1, aq);  aq = MFMA(A1[kt], bq2, aq);  aq = MFMA(A3[kt], bq3, aq);
        short8 bk1 = *(const short8*)(wkp + colb);
        short8 bk2 = *(const short8*)(wkp + 2048 + colb);
        short8 bk3 = *(const short8*)(wkp + q3off + colb);
        ak = MFMA(A1[kt], bk1, ak);  ak = MFMA(A1[kt], bk2, ak);  ak = MFMA(A3[kt], bk3, ak);
        short8 bv1 = *(const short8*)(wvp + colb);
        av = MFMA(A1[kt], bv1, av);
      }
      #pragma unroll
      for (int i = 0; i < 4; ++i) {
        int tok = 16 * w + 4 * quad + i;
        ushort a, bb, cc;
        split3t(aq[i], a, bb, cc);
        qs[tok * 56 + c] = a; qs[tok * 56 + 16 + c] = bb; qs[tok * 56 + 32 + c] = cc;
        split3t(ak[i], a, bb, cc);
        ks[tok * 56 + c] = a; ks[tok * 56 + 16 + c] = bb; ks[tok * 56 + 32 + c] = cc;
        vs[tok * 17 + c] = av[i];
      }
    }
    __syncthreads();

    // ---- phase 3 (fused): logits j-tile -> immediate softmax/top-2 fold
    {
      const ushort* qrow = qs + (16 * w + c) * 56;
      short8 aq1 = *(const short8*)(qrow + quad * 8);                      // [qh|qm]
      short8 aq3 = *(const short8*)(qrow + ((quad < 2) ? quad * 8 : 16 + quad * 8)); // [qh|ql]

      float m1[4], m2[4], psum[4];
      int   i1[4], i2[4];

      #pragma unroll
      for (int j = 0; j < 8; ++j) {
        floatx4 acc;
        #pragma unroll
        for (int i = 0; i < 4; ++i) {
          int m = 16 * w + 4 * quad + i;
          int n = 16 * j + c;
          acc[i] = bias_g[(h * N_TOK + m) * N_TOK + n] +
                   mask[(wi * N_TOK + m) * N_TOK + n];
        }
        const ushort* krow = ks + (16 * j + c) * 56;
        int bo1 = (quad & 1) * 8;
        short8 b1 = *(const short8*)(krow + bo1);            // [kh|kh]
        short8 b2 = *(const short8*)(krow + 16 + bo1);       // [km|km]
        short8 b3 = *(const short8*)(krow + ((quad < 2) ? 32 + quad * 8
                                                        : (quad - 2) * 8)); // [kl|kh]
        acc = MFMA(aq1, b1, acc);
        acc = MFMA(aq1, b2, acc);
        acc = MFMA(aq3, b3, acc);

        if (j == 0) {
          #pragma unroll
          for (int i = 0; i < 4; ++i) {
            m1[i] = acc[i]; i1[i] = c;
            m2[i] = -__builtin_inff(); i2[i] = -1;
            psum[i] = 1.0f;
          }
        } else {
          #pragma unroll
          for (int i = 0; i < 4; ++i) {
            float v = acc[i]; int col = 16 * j + c;
            bool g1 = v > m1[i];
            float e = __expf(g1 ? (m1[i] - v) : (v - m1[i]));
            psum[i] = g1 ? (psum[i] * e + 1.0f) : (psum[i] + e);
            bool g2 = (!g1) && (v > m2[i]);
            m2[i] = g1 ? m1[i] : (g2 ? v : m2[i]);
            i2[i] = g1 ? i1[i] : (g2 ? col : i2[i]);
            m1[i] = g1 ? v : m1[i];
            i1[i] = g1 ? col : i1[i];
          }
        }
      }

      // ---- cross-lane reduce over the 16 columns held by the quad's lanes
      #pragma unroll
      for (int i = 0; i < 4; ++i) {
        float M1 = m1[i], M2 = m2[i], PS = psum[i];
        int I1 = i1[i], I2 = i2[i];
        #pragma unroll
        for (int d = 1; d < 16; d <<= 1) {
          float om1 = __shfl_xor(M1, d); int oi1 = __shfl_xor(I1, d);
          float om2 = __shfl_xor(M2, d); int oi2 = __shfl_xor(I2, d);
          float ops = __shfl_xor(PS, d);
          bool aw = (M1 > om1) || (M1 == om1 && I1 < oi1);
          float M  = aw ? M1 : om1;  int I  = aw ? I1 : oi1;
          float lv = aw ? om1 : M1;  int li = aw ? oi1 : I1;
          float sv = aw ? M2 : om2;  int si = aw ? I2 : oi2;
          bool sb = (sv > lv) || (sv == lv && si < li);
          float e = __expf(lv - M);
          PS = (aw ? PS : ops) + (aw ? ops : PS) * e;
          M1 = M; I1 = I;
          M2 = sb ? sv : lv; I2 = sb ? si : li;
        }
        float p1 = 1.0f / PS;
        float p2 = __expf(M2 - M1) * p1;
        int tok = 16 * w + 4 * quad + i;
        float o = p1 * vs[I1 * 17 + c] + p2 * vs[I2 * 17 + c];
        xo[tok * 40 + (h & 1) * 16 + c] = f2bf(o);
      }
    }

    // ---- phase 4: out-projection, K=32 per head pair, persistent acc
    if (h & 1) {
      const ushort* wptp = wpt_g + (size_t)(h >> 1) * 4096;
      short8 a = *(const short8*)(xo + (16 * w + c) * 40 + quad * 8);
      #pragma unroll
      for (int j = 0; j < 8; ++j) {
        short8 bf = *(const short8*)(wptp + (16 * j + c) * 32 + quad * 8);
        oacc[j] = MFMA(a, bf, oacc[j]);
      }
    }
    __syncthreads();
  }

  // ---- epilogue: + bproj, fp32 store
  #pragma unroll
  for (int j = 0; j < 8; ++j) {
    float bp = bproj[16 * j + c];
    #pragma unroll
    for (int i = 0; i < 4; ++i) {
      int row = 16 * w + 4 * quad + i;
      out[((size_t)b * N_TOK + row) * C_DIM + 16 * j + c] = oacc[j][i] + bp;
    }
  }
}

extern "C" void kernel_launch(void* const* d_in, const int* in_sizes, int n_in,
                              void* d_out, int out_size, void* d_ws, size_t ws_size,
                              hipStream_t stream) {
  const float* x     = (const float*)d_in[0];
  const float* mask  = (const float*)d_in[1];
  const float* Wq    = (const float*)d_in[2];
  const float* Wkv   = (const float*)d_in[3];
  const float* Wproj = (const float*)d_in[4];
  const float* bproj = (const float*)d_in[5];
  const float* btab  = (const float*)d_in[6];
  const int*   ridx  = (const int*)d_in[7];
  float* outp = (float*)d_out;
  char*  ws   = (char*)d_ws;

  (void)in_sizes; (void)n_in; (void)out_size; (void)ws_size;

  hipFuncSetAttribute(reinterpret_cast<const void*>(wattn_kernel),
                      hipFuncAttributeMaxDynamicSharedMemorySize, 47616);

  // 131072 bias + 4*16384 weight-split tasks = 196608 -> 384 blocks
  prep_kernel<<<384, 512, 0, stream>>>(ridx, btab, Wq, Wkv, Wproj, ws);
  wattn_kernel<<<B_TOT, 512, 47616, stream>>>(x, mask, bproj, ws, outp);
}

// Round 4
// 404.410 us; speedup vs baseline: 2.0918x; 1.7700x over previous
//
#include <hip/hip_runtime.h>
#include <hip/hip_bf16.h>
#include <stdint.h>

typedef __attribute__((ext_vector_type(8))) short short8;
typedef __attribute__((ext_vector_type(4))) float floatx4;

#define B_TOT 1024
#define N_TOK 128
#define C_DIM 128
#define NHEAD 8
#define NW_MASK 64

// ---- workspace layout (bytes) ----
// BIAS: [8][128][128] fp32
// WALL: per head (30464 B, LDS-image): wq[3][16][136]us | wk[3][16][136]us | wv[16][136]us
// WPT : [4hp][128n][32kk] ushort
#define BIAS_OFF 0
#define WALL_OFF 524288
#define WHEAD_BYTES 30464
#define WPT_OFF 768000          // 524288 + 8*30464
#define WS_BYTES 800768

// ---- LDS layout (bytes) ----
#define QS_LDS 0                // [128][56] bf16   14336
#define KS_LDS 14336            // [128][56] bf16   14336
#define VS_LDS 28672            // [128][17] fp32    8704
#define XO_LDS 37376            // [128][40] bf16   10240
#define WB_LDS 47616            // 2 x 30720  W double-buffer
#define WPTB_LDS 109056         // 2 x 8192   Wproj^T double-buffer
#define LDS_BYTES 125440

#define MFMA(a, b, c) __builtin_amdgcn_mfma_f32_16x16x32_bf16((a), (b), (c), 0, 0, 0)

__device__ __forceinline__ float bf2f(ushort u) {
  union { uint32_t u; float f; } v; v.u = ((uint32_t)u) << 16; return v.f;
}
__device__ __forceinline__ ushort f2bf(float f) {
  uint32_t u = __float_as_uint(f);
  return (ushort)((u + 0x7FFFu + ((u >> 16) & 1u)) >> 16);  // RNE
}
__device__ __forceinline__ void split3(float f, ushort& h, ushort& m, ushort& l) {
  h = f2bf(f);  float r  = f - bf2f(h);
  m = f2bf(r);  float r2 = r - bf2f(m);
  l = f2bf(r2);
}
__device__ __forceinline__ void split3t(float f, ushort& h, ushort& m, ushort& l) {
  h = (ushort)(__float_as_uint(f) >> 16);
  float r  = f - bf2f(h);
  m = (ushort)(__float_as_uint(r) >> 16);
  float r2 = r - bf2f(m);
  l = f2bf(r2);
}

// async 16B/lane global->LDS DMA (wave-uniform LDS base + lane*16)
__device__ __forceinline__ void dma16(const void* g, void* l_) {
  __builtin_amdgcn_global_load_lds((const __attribute__((address_space(1))) void*)g,
                                   (__attribute__((address_space(3))) void*)l_,
                                   16, 0, 0);
}

// ---------------------------------------------------------------------------
// Prologue: bias gather + all weight splits, once. W written as the padded
// LDS image so wattn stages it with pure linear DMA.
// ---------------------------------------------------------------------------
__global__ __launch_bounds__(512)
void prep_kernel(const int* __restrict__ rel_index, const float* __restrict__ table,
                 const float* __restrict__ Wq, const float* __restrict__ Wkv,
                 const float* __restrict__ Wproj, char* __restrict__ ws) {
  float*  bias_g = (float*)(ws + BIAS_OFF);
  ushort* wpt_g  = (ushort*)(ws + WPT_OFF);

  int idx = blockIdx.x * 512 + threadIdx.x;
  if (idx < 131072) {
    int h = idx >> 14, mn = idx & 16383;
    bias_g[idx] = table[rel_index[mn] * NHEAD + h];
  } else if (idx < 131072 + 16384) {
    int t = idx - 131072;                 // h*2048 + oc*128 + kk
    int h = t >> 11, r = t & 2047, oc = r >> 7, kk = r & 127;
    ushort a, bb, cc;
    split3(Wq[kk * C_DIM + h * 16 + oc] * 0.25f, a, bb, cc);
    ushort* wqp = (ushort*)(ws + WALL_OFF + h * WHEAD_BYTES);
    wqp[0 * 2176 + oc * 136 + kk] = a;
    wqp[1 * 2176 + oc * 136 + kk] = bb;
    wqp[2 * 2176 + oc * 136 + kk] = cc;
  } else if (idx < 131072 + 2 * 16384) {
    int t = idx - 131072 - 16384;
    int h = t >> 11, r = t & 2047, oc = r >> 7, kk = r & 127;
    ushort a, bb, cc;
    split3(Wkv[kk * (2 * C_DIM) + h * 16 + oc], a, bb, cc);
    ushort* wkp = (ushort*)(ws + WALL_OFF + h * WHEAD_BYTES) + 6528;
    wkp[0 * 2176 + oc * 136 + kk] = a;
    wkp[1 * 2176 + oc * 136 + kk] = bb;
    wkp[2 * 2176 + oc * 136 + kk] = cc;
  } else if (idx < 131072 + 3 * 16384) {
    int t = idx - 131072 - 2 * 16384;
    int h = t >> 11, r = t & 2047, oc = r >> 7, kk = r & 127;
    ushort* wvp = (ushort*)(ws + WALL_OFF + h * WHEAD_BYTES) + 13056;
    wvp[oc * 136 + kk] = f2bf(Wkv[kk * (2 * C_DIM) + C_DIM + h * 16 + oc]);
  } else if (idx < 131072 + 4 * 16384) {
    int t = idx - 131072 - 3 * 16384;     // hp*4096 + n*32 + kk
    int hp = t >> 12, r = t & 4095, n = r >> 5, kk = r & 31;
    wpt_g[t] = f2bf(Wproj[(hp * 32 + kk) * C_DIM + n]);
  }
}

// ---------------------------------------------------------------------------
// Fused window attention. 512 threads = 8 waves; wave w owns rows 16w..16w+15.
// B-operands (presplit W) are staged global->LDS via async DMA, double-
// buffered one head ahead; drained for free by the existing barriers.
// ---------------------------------------------------------------------------
__global__ __launch_bounds__(512, 2)
void wattn_kernel(const float* __restrict__ x, const float* __restrict__ mask,
                  const float* __restrict__ bproj, const char* __restrict__ ws,
                  float* __restrict__ out) {
  extern __shared__ char smem[];
  ushort* qs = (ushort*)(smem + QS_LDS);
  ushort* ks = (ushort*)(smem + KS_LDS);
  float*  vs = (float*)(smem + VS_LDS);
  ushort* xo = (ushort*)(smem + XO_LDS);

  const float* bias_g = (const float*)(ws + BIAS_OFF);

  const int tid  = threadIdx.x;
  const int w    = tid >> 6;
  const int l    = tid & 63;
  const int quad = l >> 4;
  const int c    = l & 15;
  const int b    = blockIdx.x;
  const int wi   = b & (NW_MASK - 1);

  // ---- issue DMA for head 0 W and pair 0 Wproj^T
  {
    const char* src = ws + WALL_OFF;     // head 0
    char* dst = smem + WB_LDS;           // buf 0
    #pragma unroll
    for (int t = 0; t < 4; ++t) {
      int ch = t * 8 + w;
      if (ch < 30) dma16(src + ch * 1024 + l * 16, dst + ch * 1024 + l * 16);
    }
    dma16(ws + WPT_OFF + w * 1024 + l * 16, smem + WPTB_LDS + w * 1024 + l * 16);
  }

  // ---- split this lane's head-invariant x MFMA A-fragments into registers
  short8 A1[8], A3[8];
  {
    const float* xrow = x + ((size_t)b * N_TOK + 16 * w + c) * C_DIM;
    #pragma unroll
    for (int kt = 0; kt < 8; ++kt) {
      int colb = kt * 16 + (quad & 1) * 8;
      floatx4 xa  = *(const floatx4*)(xrow + colb);
      floatx4 xb2 = *(const floatx4*)(xrow + colb + 4);
      short8 hi8, mi8, lo8;
      #pragma unroll
      for (int jj = 0; jj < 8; ++jj) {
        float f = (jj < 4) ? xa[jj] : xb2[jj - 4];
        ushort hh, mm, ll; split3t(f, hh, mm, ll);
        hi8[jj] = (short)hh; mi8[jj] = (short)mm; lo8[jj] = (short)ll;
      }
      A1[kt] = (quad < 2) ? hi8 : mi8;   // [xh|xm]
      A3[kt] = (quad < 2) ? hi8 : lo8;   // [xh|xl]
    }
  }

  floatx4 oacc[8];
  #pragma unroll
  for (int j = 0; j < 8; ++j) oacc[j] = (floatx4){0.f, 0.f, 0.f, 0.f};

  asm volatile("s_waitcnt vmcnt(0)" ::: "memory");
  __syncthreads();   // head-0 DMA landed

  for (int h = 0; h < NHEAD; ++h) {
    // ---- prefetch next head's W (and next pair's Wproj^T) into the other buf
    if (h < 7) {
      const char* src = ws + WALL_OFF + (h + 1) * WHEAD_BYTES;
      char* dst = smem + WB_LDS + ((h + 1) & 1) * 30720;
      #pragma unroll
      for (int t = 0; t < 4; ++t) {
        int ch = t * 8 + w;
        if (ch < 30) dma16(src + ch * 1024 + l * 16, dst + ch * 1024 + l * 16);
      }
      if (h & 1) {
        int np = (h + 1) >> 1;           // next pair
        dma16(ws + WPT_OFF + np * 8192 + w * 1024 + l * 16,
              smem + WPTB_LDS + (np & 1) * 8192 + w * 1024 + l * 16);
      }
    }

    // ---- phase 2: q,k (6-term split) and v (2-term) projections; B from LDS
    {
      floatx4 aq = (floatx4){0.f,0.f,0.f,0.f};
      floatx4 ak = (floatx4){0.f,0.f,0.f,0.f};
      floatx4 av = (floatx4){0.f,0.f,0.f,0.f};
      const ushort* wh  = (const ushort*)(smem + WB_LDS + (h & 1) * 30720);
      const ushort* wqp = wh + c * 136;             // plane stride 2176 us
      const ushort* wkp = wh + 6528 + c * 136;
      const ushort* wvp = wh + 13056 + c * 136;
      const int q3off = (quad < 2) ? 2 * 2176 : 0;  // wql for xh-lanes, wqh for xl-lanes
      #pragma unroll
      for (int kt = 0; kt < 8; ++kt) {
        int colb = kt * 16 + (quad & 1) * 8;
        short8 bq1 = *(const short8*)(wqp + colb);
        short8 bq2 = *(const short8*)(wqp + 2176 + colb);
        short8 bq3 = *(const short8*)(wqp + q3off + colb);
        aq = MFMA(A1[kt], bq1, aq);  aq = MFMA(A1[kt], bq2, aq);  aq = MFMA(A3[kt], bq3, aq);
        short8 bk1 = *(const short8*)(wkp + colb);
        short8 bk2 = *(const short8*)(wkp + 2176 + colb);
        short8 bk3 = *(const short8*)(wkp + q3off + colb);
        ak = MFMA(A1[kt], bk1, ak);  ak = MFMA(A1[kt], bk2, ak);  ak = MFMA(A3[kt], bk3, ak);
        short8 bv1 = *(const short8*)(wvp + colb);
        av = MFMA(A1[kt], bv1, av);
      }
      #pragma unroll
      for (int i = 0; i < 4; ++i) {
        int tok = 16 * w + 4 * quad + i;
        ushort a, bb, cc;
        split3t(aq[i], a, bb, cc);
        qs[tok * 56 + c] = a; qs[tok * 56 + 16 + c] = bb; qs[tok * 56 + 32 + c] = cc;
        split3t(ak[i], a, bb, cc);
        ks[tok * 56 + c] = a; ks[tok * 56 + 16 + c] = bb; ks[tok * 56 + 32 + c] = cc;
        vs[tok * 17 + c] = av[i];
      }
    }
    __syncthreads();   // also drains this head's prefetch DMA (vmcnt0 at barrier)

    // ---- phase 3 (fused): logits j-tile -> immediate softmax/top-2 fold
    {
      const ushort* qrow = qs + (16 * w + c) * 56;
      short8 aq1 = *(const short8*)(qrow + quad * 8);                      // [qh|qm]
      short8 aq3 = *(const short8*)(qrow + ((quad < 2) ? quad * 8 : 16 + quad * 8)); // [qh|ql]

      float m1[4], m2[4], psum[4];
      int   i1[4], i2[4];

      #pragma unroll
      for (int j = 0; j < 8; ++j) {
        floatx4 acc;
        #pragma unroll
        for (int i = 0; i < 4; ++i) {
          int m = 16 * w + 4 * quad + i;
          int n = 16 * j + c;
          acc[i] = bias_g[(h * N_TOK + m) * N_TOK + n] +
                   mask[(wi * N_TOK + m) * N_TOK + n];
        }
        const ushort* krow = ks + (16 * j + c) * 56;
        int bo1 = (quad & 1) * 8;
        short8 b1 = *(const short8*)(krow + bo1);            // [kh|kh]
        short8 b2 = *(const short8*)(krow + 16 + bo1);       // [km|km]
        short8 b3 = *(const short8*)(krow + ((quad < 2) ? 32 + quad * 8
                                                        : (quad - 2) * 8)); // [kl|kh]
        acc = MFMA(aq1, b1, acc);
        acc = MFMA(aq1, b2, acc);
        acc = MFMA(aq3, b3, acc);

        if (j == 0) {
          #pragma unroll
          for (int i = 0; i < 4; ++i) {
            m1[i] = acc[i]; i1[i] = c;
            m2[i] = -__builtin_inff(); i2[i] = -1;
            psum[i] = 1.0f;
          }
        } else {
          #pragma unroll
          for (int i = 0; i < 4; ++i) {
            float v = acc[i]; int col = 16 * j + c;
            bool g1 = v > m1[i];
            float e = __expf(g1 ? (m1[i] - v) : (v - m1[i]));
            psum[i] = g1 ? (psum[i] * e + 1.0f) : (psum[i] + e);
            bool g2 = (!g1) && (v > m2[i]);
            m2[i] = g1 ? m1[i] : (g2 ? v : m2[i]);
            i2[i] = g1 ? i1[i] : (g2 ? col : i2[i]);
            m1[i] = g1 ? v : m1[i];
            i1[i] = g1 ? col : i1[i];
          }
        }
      }

      // ---- cross-lane reduce over the 16 columns held by the quad's lanes
      #pragma unroll
      for (int i = 0; i < 4; ++i) {
        float M1 = m1[i], M2 = m2[i], PS = psum[i];
        int I1 = i1[i], I2 = i2[i];
        #pragma unroll
        for (int d = 1; d < 16; d <<= 1) {
          float om1 = __shfl_xor(M1, d); int oi1 = __shfl_xor(I1, d);
          float om2 = __shfl_xor(M2, d); int oi2 = __shfl_xor(I2, d);
          float ops = __shfl_xor(PS, d);
          bool aw = (M1 > om1) || (M1 == om1 && I1 < oi1);
          float M  = aw ? M1 : om1;  int I  = aw ? I1 : oi1;
          float lv = aw ? om1 : M1;  int li = aw ? oi1 : I1;
          float sv = aw ? M2 : om2;  int si = aw ? I2 : oi2;
          bool sb = (sv > lv) || (sv == lv && si < li);
          float e = __expf(lv - M);
          PS = (aw ? PS : ops) + (aw ? ops : PS) * e;
          M1 = M; I1 = I;
          M2 = sb ? sv : lv; I2 = sb ? si : li;
        }
        float p1 = 1.0f / PS;
        float p2 = __expf(M2 - M1) * p1;
        int tok = 16 * w + 4 * quad + i;
        float o = p1 * vs[I1 * 17 + c] + p2 * vs[I2 * 17 + c];
        xo[tok * 40 + (h & 1) * 16 + c] = f2bf(o);
      }
    }

    // ---- phase 4: out-projection, K=32 per head pair, persistent acc
    if (h & 1) {
      const ushort* wptp = (const ushort*)(smem + WPTB_LDS + ((h >> 1) & 1) * 8192);
      short8 a = *(const short8*)(xo + (16 * w + c) * 40 + quad * 8);
      #pragma unroll
      for (int j = 0; j < 8; ++j) {
        short8 bf = *(const short8*)(wptp + (16 * j + c) * 32 + quad * 8);
        oacc[j] = MFMA(a, bf, oacc[j]);
      }
    }
    __syncthreads();
  }

  // ---- epilogue: + bproj, fp32 store
  #pragma unroll
  for (int j = 0; j < 8; ++j) {
    float bp = bproj[16 * j + c];
    #pragma unroll
    for (int i = 0; i < 4; ++i) {
      int row = 16 * w + 4 * quad + i;
      out[((size_t)b * N_TOK + row) * C_DIM + 16 * j + c] = oacc[j][i] + bp;
    }
  }
}

extern "C" void kernel_launch(void* const* d_in, const int* in_sizes, int n_in,
                              void* d_out, int out_size, void* d_ws, size_t ws_size,
                              hipStream_t stream) {
  const float* x     = (const float*)d_in[0];
  const float* mask  = (const float*)d_in[1];
  const float* Wq    = (const float*)d_in[2];
  const float* Wkv   = (const float*)d_in[3];
  const float* Wproj = (const float*)d_in[4];
  const float* bproj = (const float*)d_in[5];
  const float* btab  = (const float*)d_in[6];
  const int*   ridx  = (const int*)d_in[7];
  float* outp = (float*)d_out;
  char*  ws   = (char*)d_ws;

  (void)in_sizes; (void)n_in; (void)out_size; (void)ws_size;

  hipFuncSetAttribute(reinterpret_cast<const void*>(wattn_kernel),
                      hipFuncAttributeMaxDynamicSharedMemorySize, LDS_BYTES);

  // 131072 bias + 4*16384 weight-split tasks = 196608 -> 384 blocks
  prep_kernel<<<384, 512, 0, stream>>>(ridx, btab, Wq, Wkv, Wproj, ws);
  wattn_kernel<<<B_TOT, 512, LDS_BYTES, stream>>>(x, mask, bproj, ws, outp);
}

// Round 5
// 381.639 us; speedup vs baseline: 2.2166x; 1.0597x over previous
//
#include <hip/hip_runtime.h>
#include <hip/hip_bf16.h>
#include <stdint.h>

typedef __attribute__((ext_vector_type(8))) short short8;
typedef __attribute__((ext_vector_type(4))) float floatx4;

#define B_TOT 1024
#define N_TOK 128
#define C_DIM 128
#define NHEAD 8
#define NW_MASK 64

// ---- workspace layout (bytes) ----
// BIAS: [8][128][128] fp32
// WALL: per head (30464 B, LDS-image): wq[3][16][136]us | wk[3][16][136]us | wv[16][136]us
// WPT : [4hp][128n][32kk] ushort
#define BIAS_OFF 0
#define WALL_OFF 524288
#define WHEAD_BYTES 30464
#define WPT_OFF 768000          // 524288 + 8*30464
#define WS_BYTES 800768

// ---- LDS layout (bytes) ----
#define QS_LDS 0                // [128][56] bf16        14336
#define KS_LDS 14336            // 2 x [128][56] bf16    28672 (double buffer)
#define VS_LDS 43008            // 2 x [128][17] fp32    17408 (double buffer)
#define XO_LDS 60416            // [128][40] bf16        10240
#define WB_LDS 70656            // 2 x 30720  W double-buffer
#define WPTB_LDS 132096         // 2 x 8192   Wproj^T double-buffer
#define LDS_BYTES 148480

#define MFMA(a, b, c) __builtin_amdgcn_mfma_f32_16x16x32_bf16((a), (b), (c), 0, 0, 0)

__device__ __forceinline__ float bf2f(ushort u) {
  union { uint32_t u; float f; } v; v.u = ((uint32_t)u) << 16; return v.f;
}
__device__ __forceinline__ ushort f2bf(float f) {
  uint32_t u = __float_as_uint(f);
  return (ushort)((u + 0x7FFFu + ((u >> 16) & 1u)) >> 16);  // RNE
}
__device__ __forceinline__ void split3(float f, ushort& h, ushort& m, ushort& l) {
  h = f2bf(f);  float r  = f - bf2f(h);
  m = f2bf(r);  float r2 = r - bf2f(m);
  l = f2bf(r2);
}
__device__ __forceinline__ void split3t(float f, ushort& h, ushort& m, ushort& l) {
  h = (ushort)(__float_as_uint(f) >> 16);
  float r  = f - bf2f(h);
  m = (ushort)(__float_as_uint(r) >> 16);
  float r2 = r - bf2f(m);
  l = f2bf(r2);
}

// async 16B/lane global->LDS DMA (wave-uniform LDS base + lane*16)
__device__ __forceinline__ void dma16(const void* g, void* l_) {
  __builtin_amdgcn_global_load_lds((const __attribute__((address_space(1))) void*)g,
                                   (__attribute__((address_space(3))) void*)l_,
                                   16, 0, 0);
}

// ---------------------------------------------------------------------------
// Prologue: bias gather + all weight splits, once. W written as the padded
// LDS image so wattn stages it with pure linear DMA.
// ---------------------------------------------------------------------------
__global__ __launch_bounds__(512)
void prep_kernel(const int* __restrict__ rel_index, const float* __restrict__ table,
                 const float* __restrict__ Wq, const float* __restrict__ Wkv,
                 const float* __restrict__ Wproj, char* __restrict__ ws) {
  float*  bias_g = (float*)(ws + BIAS_OFF);
  ushort* wpt_g  = (ushort*)(ws + WPT_OFF);

  int idx = blockIdx.x * 512 + threadIdx.x;
  if (idx < 131072) {
    int h = idx >> 14, mn = idx & 16383;
    bias_g[idx] = table[rel_index[mn] * NHEAD + h];
  } else if (idx < 131072 + 16384) {
    int t = idx - 131072;                 // h*2048 + oc*128 + kk
    int h = t >> 11, r = t & 2047, oc = r >> 7, kk = r & 127;
    ushort a, bb, cc;
    split3(Wq[kk * C_DIM + h * 16 + oc] * 0.25f, a, bb, cc);
    ushort* wqp = (ushort*)(ws + WALL_OFF + h * WHEAD_BYTES);
    wqp[0 * 2176 + oc * 136 + kk] = a;
    wqp[1 * 2176 + oc * 136 + kk] = bb;
    wqp[2 * 2176 + oc * 136 + kk] = cc;
  } else if (idx < 131072 + 2 * 16384) {
    int t = idx - 131072 - 16384;
    int h = t >> 11, r = t & 2047, oc = r >> 7, kk = r & 127;
    ushort a, bb, cc;
    split3(Wkv[kk * (2 * C_DIM) + h * 16 + oc], a, bb, cc);
    ushort* wkp = (ushort*)(ws + WALL_OFF + h * WHEAD_BYTES) + 6528;
    wkp[0 * 2176 + oc * 136 + kk] = a;
    wkp[1 * 2176 + oc * 136 + kk] = bb;
    wkp[2 * 2176 + oc * 136 + kk] = cc;
  } else if (idx < 131072 + 3 * 16384) {
    int t = idx - 131072 - 2 * 16384;
    int h = t >> 11, r = t & 2047, oc = r >> 7, kk = r & 127;
    ushort* wvp = (ushort*)(ws + WALL_OFF + h * WHEAD_BYTES) + 13056;
    wvp[oc * 136 + kk] = f2bf(Wkv[kk * (2 * C_DIM) + C_DIM + h * 16 + oc]);
  } else if (idx < 131072 + 4 * 16384) {
    int t = idx - 131072 - 3 * 16384;     // hp*4096 + n*32 + kk
    int hp = t >> 12, r = t & 4095, n = r >> 5, kk = r & 31;
    wpt_g[t] = f2bf(Wproj[(hp * 32 + kk) * C_DIM + n]);
  }
}

// ---------------------------------------------------------------------------
// Fused window attention. 512 threads = 8 waves; wave w owns rows 16w..16w+15.
// vs round 4: (1) ks/vs double-buffered -> ONE barrier per head (8 vs 16);
// (2) softmax accumulates raw exp(v) (no running-max rescale; |logit| << 80
//     so fp32 is safe) -> fold exps are independent, butterfly is cheap;
// (3) logits MFMA chain starts from acc=0; bias+mask added after -> VMEM
//     loads no longer gate the MFMA chain.
// ---------------------------------------------------------------------------
__global__ __launch_bounds__(512, 2)
void wattn_kernel(const float* __restrict__ x, const float* __restrict__ mask,
                  const float* __restrict__ bproj, const char* __restrict__ ws,
                  float* __restrict__ out) {
  extern __shared__ char smem[];
  ushort* qs = (ushort*)(smem + QS_LDS);
  ushort* xo = (ushort*)(smem + XO_LDS);

  const float* bias_g = (const float*)(ws + BIAS_OFF);

  const int tid  = threadIdx.x;
  const int w    = tid >> 6;
  const int l    = tid & 63;
  const int quad = l >> 4;
  const int c    = l & 15;
  const int b    = blockIdx.x;
  const int wi   = b & (NW_MASK - 1);

  // ---- issue DMA for head 0 W and pair 0 Wproj^T
  {
    const char* src = ws + WALL_OFF;     // head 0
    char* dst = smem + WB_LDS;           // buf 0
    #pragma unroll
    for (int t = 0; t < 4; ++t) {
      int ch = t * 8 + w;
      if (ch < 30) dma16(src + ch * 1024 + l * 16, dst + ch * 1024 + l * 16);
    }
    dma16(ws + WPT_OFF + w * 1024 + l * 16, smem + WPTB_LDS + w * 1024 + l * 16);
  }

  // ---- split this lane's head-invariant x MFMA A-fragments into registers
  short8 A1[8], A3[8];
  {
    const float* xrow = x + ((size_t)b * N_TOK + 16 * w + c) * C_DIM;
    #pragma unroll
    for (int kt = 0; kt < 8; ++kt) {
      int colb = kt * 16 + (quad & 1) * 8;
      floatx4 xa  = *(const floatx4*)(xrow + colb);
      floatx4 xb2 = *(const floatx4*)(xrow + colb + 4);
      short8 hi8, mi8, lo8;
      #pragma unroll
      for (int jj = 0; jj < 8; ++jj) {
        float f = (jj < 4) ? xa[jj] : xb2[jj - 4];
        ushort hh, mm, ll; split3t(f, hh, mm, ll);
        hi8[jj] = (short)hh; mi8[jj] = (short)mm; lo8[jj] = (short)ll;
      }
      A1[kt] = (quad < 2) ? hi8 : mi8;   // [xh|xm]
      A3[kt] = (quad < 2) ? hi8 : lo8;   // [xh|xl]
    }
  }

  floatx4 oacc[8];
  #pragma unroll
  for (int j = 0; j < 8; ++j) oacc[j] = (floatx4){0.f, 0.f, 0.f, 0.f};

  asm volatile("s_waitcnt vmcnt(0)" ::: "memory");
  __syncthreads();   // head-0 DMA landed

  for (int h = 0; h < NHEAD; ++h) {
    ushort* ks_c = (ushort*)(smem + KS_LDS + (h & 1) * 14336);
    float*  vs_c = (float*)(smem + VS_LDS + (h & 1) * 8704);

    // ---- prefetch next head's W (and next pair's Wproj^T) into the other buf
    if (h < 7) {
      const char* src = ws + WALL_OFF + (h + 1) * WHEAD_BYTES;
      char* dst = smem + WB_LDS + ((h + 1) & 1) * 30720;
      #pragma unroll
      for (int t = 0; t < 4; ++t) {
        int ch = t * 8 + w;
        if (ch < 30) dma16(src + ch * 1024 + l * 16, dst + ch * 1024 + l * 16);
      }
      if (h & 1) {
        int np = (h + 1) >> 1;           // next pair
        dma16(ws + WPT_OFF + np * 8192 + w * 1024 + l * 16,
              smem + WPTB_LDS + (np & 1) * 8192 + w * 1024 + l * 16);
      }
    }

    // ---- phase 2: q,k (6-term split) and v (2-term) projections; B from LDS
    {
      floatx4 aq = (floatx4){0.f,0.f,0.f,0.f};
      floatx4 ak = (floatx4){0.f,0.f,0.f,0.f};
      floatx4 av = (floatx4){0.f,0.f,0.f,0.f};
      const ushort* wh  = (const ushort*)(smem + WB_LDS + (h & 1) * 30720);
      const ushort* wqp = wh + c * 136;             // plane stride 2176 us
      const ushort* wkp = wh + 6528 + c * 136;
      const ushort* wvp = wh + 13056 + c * 136;
      const int q3off = (quad < 2) ? 2 * 2176 : 0;  // wql for xh-lanes, wqh for xl-lanes
      #pragma unroll
      for (int kt = 0; kt < 8; ++kt) {
        int colb = kt * 16 + (quad & 1) * 8;
        short8 bq1 = *(const short8*)(wqp + colb);
        short8 bq2 = *(const short8*)(wqp + 2176 + colb);
        short8 bq3 = *(const short8*)(wqp + q3off + colb);
        aq = MFMA(A1[kt], bq1, aq);  aq = MFMA(A1[kt], bq2, aq);  aq = MFMA(A3[kt], bq3, aq);
        short8 bk1 = *(const short8*)(wkp + colb);
        short8 bk2 = *(const short8*)(wkp + 2176 + colb);
        short8 bk3 = *(const short8*)(wkp + q3off + colb);
        ak = MFMA(A1[kt], bk1, ak);  ak = MFMA(A1[kt], bk2, ak);  ak = MFMA(A3[kt], bk3, ak);
        short8 bv1 = *(const short8*)(wvp + colb);
        av = MFMA(A1[kt], bv1, av);
      }
      #pragma unroll
      for (int i = 0; i < 4; ++i) {
        int tok = 16 * w + 4 * quad + i;
        ushort a, bb, cc;
        split3t(aq[i], a, bb, cc);
        qs[tok * 56 + c] = a; qs[tok * 56 + 16 + c] = bb; qs[tok * 56 + 32 + c] = cc;
        split3t(ak[i], a, bb, cc);
        ks_c[tok * 56 + c] = a; ks_c[tok * 56 + 16 + c] = bb; ks_c[tok * 56 + 32 + c] = cc;
        vs_c[tok * 17 + c] = av[i];
      }
    }
    __syncthreads();   // the ONLY barrier this head; also drains prefetch DMA

    // ---- phase 3 (fused): logits j-tile -> raw-exp softmax + top-2 fold
    {
      const ushort* qrow = qs + (16 * w + c) * 56;
      short8 aq1 = *(const short8*)(qrow + quad * 8);                      // [qh|qm]
      short8 aq3 = *(const short8*)(qrow + ((quad < 2) ? quad * 8 : 16 + quad * 8)); // [qh|ql]

      float m1[4], m2[4], psum[4];
      int   i1[4], i2[4];
      #pragma unroll
      for (int i = 0; i < 4; ++i) {
        m1[i] = -__builtin_inff(); i1[i] = 0;
        m2[i] = -__builtin_inff(); i2[i] = -1;
        psum[i] = 0.0f;
      }

      #pragma unroll
      for (int j = 0; j < 8; ++j) {
        floatx4 acc = (floatx4){0.f, 0.f, 0.f, 0.f};
        const ushort* krow = ks_c + (16 * j + c) * 56;
        int bo1 = (quad & 1) * 8;
        short8 b1 = *(const short8*)(krow + bo1);            // [kh|kh]
        short8 b2 = *(const short8*)(krow + 16 + bo1);       // [km|km]
        short8 b3 = *(const short8*)(krow + ((quad < 2) ? 32 + quad * 8
                                                        : (quad - 2) * 8)); // [kl|kh]
        acc = MFMA(aq1, b1, acc);
        acc = MFMA(aq1, b2, acc);
        acc = MFMA(aq3, b3, acc);

        #pragma unroll
        for (int i = 0; i < 4; ++i) {
          int m = 16 * w + 4 * quad + i;
          int n = 16 * j + c;
          float v = acc[i] + bias_g[(h * N_TOK + m) * N_TOK + n] +
                             mask[(wi * N_TOK + m) * N_TOK + n];
          psum[i] += __expf(v);           // raw exp: independent, fp32-safe
          int col = 16 * j + c;
          bool g1 = v > m1[i];
          bool g2 = (!g1) && (v > m2[i]);
          m2[i] = g1 ? m1[i] : (g2 ? v : m2[i]);
          i2[i] = g1 ? i1[i] : (g2 ? col : i2[i]);
          m1[i] = g1 ? v : m1[i];
          i1[i] = g1 ? col : i1[i];
        }
      }

      // ---- cross-lane reduce over the 16 columns held by the quad's lanes
      #pragma unroll
      for (int i = 0; i < 4; ++i) {
        float M1 = m1[i], M2 = m2[i], PS = psum[i];
        int I1 = i1[i], I2 = i2[i];
        #pragma unroll
        for (int d = 1; d < 16; d <<= 1) {
          float om1 = __shfl_xor(M1, d); int oi1 = __shfl_xor(I1, d);
          float om2 = __shfl_xor(M2, d); int oi2 = __shfl_xor(I2, d);
          float ops = __shfl_xor(PS, d);
          bool aw = (M1 > om1) || (M1 == om1 && I1 < oi1);
          float lv = aw ? om1 : M1;  int li = aw ? oi1 : I1;
          float sv = aw ? M2 : om2;  int si = aw ? I2 : oi2;
          M1 = aw ? M1 : om1;  I1 = aw ? I1 : oi1;
          bool sb = (sv > lv) || (sv == lv && si < li);
          M2 = sb ? sv : lv; I2 = sb ? si : li;
          PS += ops;                       // raw psums: plain add
        }
        float inv = 1.0f / PS;
        float p1 = __expf(M1) * inv;
        float p2 = __expf(M2) * inv;
        int tok = 16 * w + 4 * quad + i;
        float o = p1 * vs_c[I1 * 17 + c] + p2 * vs_c[I2 * 17 + c];
        xo[tok * 40 + (h & 1) * 16 + c] = f2bf(o);
      }
    }

    // ---- phase 4: out-projection, K=32 per head pair, persistent acc
    if (h & 1) {
      const ushort* wptp = (const ushort*)(smem + WPTB_LDS + ((h >> 1) & 1) * 8192);
      short8 a = *(const short8*)(xo + (16 * w + c) * 40 + quad * 8);
      #pragma unroll
      for (int j = 0; j < 8; ++j) {
        short8 bf = *(const short8*)(wptp + (16 * j + c) * 32 + quad * 8);
        oacc[j] = MFMA(a, bf, oacc[j]);
      }
    }
  }

  // ---- epilogue: + bproj, fp32 store
  #pragma unroll
  for (int j = 0; j < 8; ++j) {
    float bp = bproj[16 * j + c];
    #pragma unroll
    for (int i = 0; i < 4; ++i) {
      int row = 16 * w + 4 * quad + i;
      out[((size_t)b * N_TOK + row) * C_DIM + 16 * j + c] = oacc[j][i] + bp;
    }
  }
}

extern "C" void kernel_launch(void* const* d_in, const int* in_sizes, int n_in,
                              void* d_out, int out_size, void* d_ws, size_t ws_size,
                              hipStream_t stream) {
  const float* x     = (const float*)d_in[0];
  const float* mask  = (const float*)d_in[1];
  const float* Wq    = (const float*)d_in[2];
  const float* Wkv   = (const float*)d_in[3];
  const float* Wproj = (const float*)d_in[4];
  const float* bproj = (const float*)d_in[5];
  const float* btab  = (const float*)d_in[6];
  const int*   ridx  = (const int*)d_in[7];
  float* outp = (float*)d_out;
  char*  ws   = (char*)d_ws;

  (void)in_sizes; (void)n_in; (void)out_size; (void)ws_size;

  hipFuncSetAttribute(reinterpret_cast<const void*>(wattn_kernel),
                      hipFuncAttributeMaxDynamicSharedMemorySize, LDS_BYTES);

  // 131072 bias + 4*16384 weight-split tasks = 196608 -> 384 blocks
  prep_kernel<<<384, 512, 0, stream>>>(ridx, btab, Wq, Wkv, Wproj, ws);
  wattn_kernel<<<B_TOT, 512, LDS_BYTES, stream>>>(x, mask, bproj, ws, outp);
}